// Round 3
// baseline (543.995 us; speedup 1.0000x reference)
//
#include <hip/hip_runtime.h>
#include <hip/hip_bf16.h>

// Problem: B=2, L=2048, E=1024, H=16, D=64. Mask int32.
// Float tensors may arrive as fp32 (reference dtype) or bf16 (harness downcast)
// — detected on-device, wave-uniform dual load paths.
// ws: [flag:4B] ... qp[B,H,L,D] @2MB | kp @10MB | vpT[B,H,D,L] @18MB | attn_out @26MB (bf16 each)

#define B_ 2
#define L_ 2048
#define E_ 1024
#define H_ 16
#define D_ 64

typedef __attribute__((ext_vector_type(8))) short s8v;     // 8 bf16
typedef __attribute__((ext_vector_type(4))) float f4v;     // 4 fp32

__device__ __forceinline__ f4v mfma16(s8v a, s8v b, f4v c) {
    return __builtin_amdgcn_mfma_f32_16x16x32_bf16(a, b, c, 0, 0, 0);
}

__device__ __forceinline__ ushort bf16bits(float f) {
    __hip_bfloat16 h = __float2bfloat16(f);
    return *(ushort*)&h;
}

// Load 8 consecutive "reference float" elements at index idx as bf16 frag half.
__device__ __forceinline__ s8v ld8_dual(const void* p, size_t idx, bool isf32) {
    if (isf32) {
        const float* pf = (const float*)p + idx;
        f4v f0 = *(const f4v*)pf;
        f4v f1 = *(const f4v*)(pf + 4);
        s8v r;
        r[0] = (short)bf16bits(f0[0]); r[1] = (short)bf16bits(f0[1]);
        r[2] = (short)bf16bits(f0[2]); r[3] = (short)bf16bits(f0[3]);
        r[4] = (short)bf16bits(f1[0]); r[5] = (short)bf16bits(f1[1]);
        r[6] = (short)bf16bits(f1[2]); r[7] = (short)bf16bits(f1[3]);
        return r;
    }
    return *(const s8v*)((const __hip_bfloat16*)p + idx);
}

__device__ __forceinline__ s8v ld8_ws(const __hip_bfloat16* p) {
    return *(const s8v*)p;   // internal ws buffers are always bf16, 16B aligned
}

// ---------------- dtype detection ----------------
// Interpret first 4096 elements of query as bf16. If the buffer actually holds
// fp32, half of those "bf16"s are random mantissa bits -> ~22% have exponent
// >= 0x8E (|x| >= 2^15) or 0xFF. True bf16 of N(0,1) data: zero such values.
__global__ void detect_kernel(const ushort* __restrict__ q, int* __restrict__ flag) {
    __shared__ int cnt;
    if (threadIdx.x == 0) cnt = 0;
    __syncthreads();
    int bad = 0;
    #pragma unroll
    for (int i = 0; i < 16; ++i) {
        ushort u = q[threadIdx.x * 16 + i];
        int e = (u >> 7) & 0xFF;
        if (e >= 0x8E) ++bad;
    }
    atomicAdd(&cnt, bad);
    __syncthreads();
    if (threadIdx.x == 0) *flag = (cnt > 100) ? 1 : 0;
}

// ---------------- Q/K projection -> [B,H,L,D] bf16 ----------------
__global__ __launch_bounds__(256) void qk_proj_kernel(
    const void* __restrict__ q_in, const void* __restrict__ k_in,
    const void* __restrict__ Wq,   const void* __restrict__ Wk,
    __hip_bfloat16* __restrict__ qp, __hip_bfloat16* __restrict__ kp,
    const int* __restrict__ flag)
{
    const bool isf32 = (*flag != 0);
    const int which = blockIdx.y;            // 0=q, 1=k
    const void* X = which == 0 ? q_in : k_in;
    const void* W = which == 0 ? Wq : Wk;
    __hip_bfloat16* dst = which == 0 ? qp : kp;

    const int wave = threadIdx.x >> 6;
    const int lane = threadIdx.x & 63;
    const int quad = lane >> 4;
    const int l16  = lane & 15;
    const int m0 = (blockIdx.x * 4 + wave) * 16;   // 16 rows = 16 heads of one token

    const size_t abase = (size_t)(m0 + l16) * D_;
    s8v a0 = ld8_dual(X, abase + quad * 8, isf32);
    s8v a1 = ld8_dual(X, abase + 32 + quad * 8, isf32);

    f4v acc[4];
    #pragma unroll
    for (int nt = 0; nt < 4; ++nt) {
        const size_t bbase = (size_t)(nt * 16 + l16) * D_;
        s8v b0 = ld8_dual(W, bbase + quad * 8, isf32);
        s8v b1 = ld8_dual(W, bbase + 32 + quad * 8, isf32);
        f4v c = {0.f, 0.f, 0.f, 0.f};
        c = mfma16(a0, b0, c);
        c = mfma16(a1, b1, c);
        acc[nt] = c;
    }
    #pragma unroll
    for (int r = 0; r < 4; ++r) {
        const int m = m0 + quad * 4 + r;
        const int h = m & 15;
        const int bl = m >> 4;               // b*L + l
        const int b = bl >> 11;
        const int l = bl & (L_ - 1);
        #pragma unroll
        for (int nt = 0; nt < 4; ++nt) {
            const int e = nt * 16 + l16;
            dst[(((size_t)(b * H_ + h)) * L_ + l) * D_ + e] = __float2bfloat16(acc[nt][r]);
        }
    }
}

// ---------------- V projection (transposed output [B,H,D,L]) ----------------
__global__ __launch_bounds__(256) void v_proj_kernel(
    const void* __restrict__ v_in,   // [B,L,E]
    const void* __restrict__ Wv,     // [D,D]
    __hip_bfloat16* __restrict__ vpT,
    const int* __restrict__ flag)
{
    const bool isf32 = (*flag != 0);
    __shared__ __align__(16) ushort tile[64][72];   // [l][e], pad to 72
    const int wave = threadIdx.x >> 6;
    const int lane = threadIdx.x & 63;
    const int quad = lane >> 4;
    const int l16  = lane & 15;
    const int l0 = blockIdx.x * 64;
    const int bh = blockIdx.y;
    const int b = bh >> 4, h = bh & 15;
    const int lw = l0 + wave * 16;

    const size_t xbase = ((size_t)(b * L_ + lw + l16)) * E_ + h * D_;
    s8v a0 = ld8_dual(v_in, xbase + quad * 8, isf32);
    s8v a1 = ld8_dual(v_in, xbase + 32 + quad * 8, isf32);

    #pragma unroll
    for (int nt = 0; nt < 4; ++nt) {
        const int e = nt * 16 + l16;
        s8v b0 = ld8_dual(Wv, (size_t)e * D_ + quad * 8, isf32);
        s8v b1 = ld8_dual(Wv, (size_t)e * D_ + 32 + quad * 8, isf32);
        f4v c = {0.f, 0.f, 0.f, 0.f};
        c = mfma16(a0, b0, c);
        c = mfma16(a1, b1, c);
        #pragma unroll
        for (int r = 0; r < 4; ++r)
            tile[wave * 16 + quad * 4 + r][e] = bf16bits(c[r]);
    }
    __syncthreads();
    const int e  = threadIdx.x >> 2;
    const int lc = (threadIdx.x & 3) * 16;
    s8v s0, s1;
    #pragma unroll
    for (int i = 0; i < 8; ++i) {
        s0[i] = (short)tile[lc + i][e];
        s1[i] = (short)tile[lc + 8 + i][e];
    }
    __hip_bfloat16* drow = vpT + ((size_t)bh * D_ + e) * L_ + l0 + lc;
    *(s8v*)drow = s0;
    *(s8v*)(drow + 8) = s1;
}

// ---------------- Flash attention (ws-only inputs, bf16) ----------------
__global__ __launch_bounds__(256) void attn_kernel(
    const __hip_bfloat16* __restrict__ qp,    // [B,H,L,D]
    const __hip_bfloat16* __restrict__ kp,    // [B,H,L,D]
    const __hip_bfloat16* __restrict__ vpT,   // [B,H,D,L]
    const int* __restrict__ mask,             // [B,1,L,L]
    __hip_bfloat16* __restrict__ attn_out)    // [B,L,E]
{
    __shared__ __align__(16) ushort pbuf[4][16 * 72];   // per-wave P tile, stride 72
    const int wave = threadIdx.x >> 6;
    const int lane = threadIdx.x & 63;
    const int quad = lane >> 4;
    const int l16  = lane & 15;
    const int bh = blockIdx.y;
    const int b = bh >> 4, h = bh & 15;
    const int q0 = blockIdx.x * 64 + wave * 16;

    const __hip_bfloat16* qbase = qp + ((size_t)bh * L_ + q0) * D_;
    s8v qa0 = ld8_ws(qbase + (size_t)l16 * D_ + quad * 8);
    s8v qa1 = ld8_ws(qbase + (size_t)l16 * D_ + 32 + quad * 8);

    float m_i[4], li[4];
    #pragma unroll
    for (int r = 0; r < 4; ++r) { m_i[r] = -1.0e30f; li[r] = 0.f; }
    f4v o[4];
    #pragma unroll
    for (int nt = 0; nt < 4; ++nt) o[nt] = (f4v){0.f, 0.f, 0.f, 0.f};

    const __hip_bfloat16* kbh = kp + (size_t)bh * L_ * D_;
    const __hip_bfloat16* vbh = vpT + (size_t)bh * D_ * L_;
    const int* mrow = mask + (size_t)b * L_ * L_;

    for (int k0 = 0; k0 < L_; k0 += 64) {
        f4v s[4];
        #pragma unroll
        for (int nt = 0; nt < 4; ++nt) {
            const __hip_bfloat16* krow = kbh + (size_t)(k0 + nt * 16 + l16) * D_;
            s8v kb0 = ld8_ws(krow + quad * 8);
            s8v kb1 = ld8_ws(krow + 32 + quad * 8);
            f4v c = {0.f, 0.f, 0.f, 0.f};
            c = mfma16(qa0, kb0, c);
            c = mfma16(qa1, kb1, c);
            s[nt] = c;
        }
        // mask BEFORE scale (-1e20), then /sqrt(E)=32 — reference order
        #pragma unroll
        for (int nt = 0; nt < 4; ++nt) {
            const int col = k0 + nt * 16 + l16;
            #pragma unroll
            for (int r = 0; r < 4; ++r) {
                const int row = q0 + quad * 4 + r;
                const int mv = mrow[(size_t)row * L_ + col];
                float sv = s[nt][r];
                sv = (mv == 0) ? -1.0e20f : sv;
                s[nt][r] = sv * (1.0f / 32.0f);
            }
        }
        #pragma unroll
        for (int r = 0; r < 4; ++r) {
            float v = fmaxf(fmaxf(s[0][r], s[1][r]), fmaxf(s[2][r], s[3][r]));
            #pragma unroll
            for (int off = 1; off < 16; off <<= 1)
                v = fmaxf(v, __shfl_xor(v, off, 64));
            const float mnew = fmaxf(m_i[r], v);
            const float alpha = __expf(m_i[r] - mnew);
            m_i[r] = mnew;
            li[r] *= alpha;
            #pragma unroll
            for (int nt = 0; nt < 4; ++nt) o[nt][r] *= alpha;
        }
        float rsum[4];
        #pragma unroll
        for (int r = 0; r < 4; ++r) rsum[r] = 0.f;
        #pragma unroll
        for (int nt = 0; nt < 4; ++nt) {
            #pragma unroll
            for (int r = 0; r < 4; ++r) {
                const float p = __expf(s[nt][r] - m_i[r]);
                rsum[r] += p;
                pbuf[wave][(quad * 4 + r) * 72 + nt * 16 + l16] = bf16bits(p);
            }
        }
        #pragma unroll
        for (int r = 0; r < 4; ++r) {
            float v = rsum[r];
            #pragma unroll
            for (int off = 1; off < 16; off <<= 1)
                v += __shfl_xor(v, off, 64);
            li[r] += v;
        }
        __syncthreads();   // RAW fence: scalar P-stores -> vector P-loads
        s8v pa0 = *(const s8v*)&pbuf[wave][l16 * 72 + quad * 8];
        s8v pa1 = *(const s8v*)&pbuf[wave][l16 * 72 + 32 + quad * 8];
        #pragma unroll
        for (int nt = 0; nt < 4; ++nt) {
            const __hip_bfloat16* vrow = vbh + (size_t)(nt * 16 + l16) * L_ + k0;
            s8v vb0 = ld8_ws(vrow + quad * 8);
            s8v vb1 = ld8_ws(vrow + 32 + quad * 8);
            f4v c = o[nt];
            c = mfma16(pa0, vb0, c);
            c = mfma16(pa1, vb1, c);
            o[nt] = c;
        }
        __syncthreads();   // WAR fence before next iteration's P-stores
    }
    #pragma unroll
    for (int r = 0; r < 4; ++r) {
        const int row = q0 + quad * 4 + r;
        const float inv = 1.0f / li[r];
        #pragma unroll
        for (int nt = 0; nt < 4; ++nt) {
            const int d = nt * 16 + l16;
            attn_out[((size_t)(b * L_ + row)) * E_ + h * D_ + d] =
                __float2bfloat16(o[nt][r] * inv);
        }
    }
}

// ---------------- Output FC: out = x @ Wfc^T + bfc ----------------
__global__ __launch_bounds__(256) void fc_kernel(
    const __hip_bfloat16* __restrict__ x,     // [B*L, E] (ws, bf16)
    const void* __restrict__ Wfc,             // [E, E] dual
    const void* __restrict__ bfc,             // [E] dual
    void* __restrict__ out,                   // [B*L, E] dual
    const int* __restrict__ flag)
{
    const bool isf32 = (*flag != 0);
    const int wave = threadIdx.x >> 6;
    const int lane = threadIdx.x & 63;
    const int quad = lane >> 4;
    const int l16  = lane & 15;
    const int m0 = blockIdx.x * 64 + wave * 16;
    const int n0 = blockIdx.y * 64;

    f4v acc[4];
    #pragma unroll
    for (int nt = 0; nt < 4; ++nt) acc[nt] = (f4v){0.f, 0.f, 0.f, 0.f};

    for (int k0 = 0; k0 < E_; k0 += 32) {
        s8v a = ld8_ws(x + (size_t)(m0 + l16) * E_ + k0 + quad * 8);
        #pragma unroll
        for (int nt = 0; nt < 4; ++nt) {
            s8v bb = ld8_dual(Wfc, (size_t)(n0 + nt * 16 + l16) * E_ + k0 + quad * 8, isf32);
            acc[nt] = mfma16(a, bb, acc[nt]);
        }
    }
    #pragma unroll
    for (int r = 0; r < 4; ++r) {
        const int m = m0 + quad * 4 + r;
        #pragma unroll
        for (int nt = 0; nt < 4; ++nt) {
            const int n = n0 + nt * 16 + l16;
            const float bias = isf32 ? ((const float*)bfc)[n]
                                     : __bfloat162float(((const __hip_bfloat16*)bfc)[n]);
            const float val = acc[nt][r] + bias;
            if (isf32) ((float*)out)[(size_t)m * E_ + n] = val;
            else       ((__hip_bfloat16*)out)[(size_t)m * E_ + n] = __float2bfloat16(val);
        }
    }
}

extern "C" void kernel_launch(void* const* d_in, const int* in_sizes, int n_in,
                              void* d_out, int out_size, void* d_ws, size_t ws_size,
                              hipStream_t stream) {
    const void* query = d_in[0];
    const void* value = d_in[1];
    const void* key   = d_in[2];
    const int*  mask  = (const int*)d_in[3];
    const void* Wq  = d_in[4];
    const void* Wk  = d_in[5];
    const void* Wv  = d_in[6];
    const void* Wfc = d_in[7];
    const void* bfc = d_in[8];

    char* ws = (char*)d_ws;
    int* flag                = (int*)ws;
    __hip_bfloat16* qp       = (__hip_bfloat16*)(ws + (2u  << 20));
    __hip_bfloat16* kp       = (__hip_bfloat16*)(ws + (10u << 20));
    __hip_bfloat16* vpT      = (__hip_bfloat16*)(ws + (18u << 20));
    __hip_bfloat16* attn_out = (__hip_bfloat16*)(ws + (26u << 20));

    detect_kernel<<<1, 256, 0, stream>>>((const ushort*)query, flag);
    qk_proj_kernel<<<dim3(1024, 2), 256, 0, stream>>>(query, key, Wq, Wk, qp, kp, flag);
    v_proj_kernel<<<dim3(32, 32), 256, 0, stream>>>(value, Wv, vpT, flag);
    attn_kernel<<<dim3(32, 32), 256, 0, stream>>>(qp, kp, vpT, mask, attn_out);
    fc_kernel<<<dim3(64, 16), 256, 0, stream>>>(attn_out, Wfc, bfc, d_out, flag);
}

// Round 5
// 475.537 us; speedup vs baseline: 1.1440x; 1.1440x over previous
//
#include <hip/hip_runtime.h>
#include <hip/hip_bf16.h>

// B=2, L=2048, E=1024, H=16, D=64. Inputs fp32-or-bf16 (detected), mask int32.
// ws: flag@0 | mbits@64KB (1MB) | qp@2MB (8MB, reused for wfc_bf/bfc_bf after attn)
//     | kp@10MB | vpT@18MB | attn_out@26MB   (total 34MB)

#define B_ 2
#define L_ 2048
#define E_ 1024
#define H_ 16
#define D_ 64

typedef __attribute__((ext_vector_type(8))) short s8v;     // 8 bf16
typedef __attribute__((ext_vector_type(4))) float f4v;     // 4 fp32

__device__ __forceinline__ f4v mfma16(s8v a, s8v b, f4v c) {
    return __builtin_amdgcn_mfma_f32_16x16x32_bf16(a, b, c, 0, 0, 0);
}

__device__ __forceinline__ float fast_exp2(float x) {
    return __builtin_amdgcn_exp2f(x);   // raw v_exp_f32 (avoids glibc __exp2f clash)
}

__device__ __forceinline__ ushort bf16bits(float f) {
    __hip_bfloat16 h = __float2bfloat16(f);
    return *(ushort*)&h;
}

__device__ __forceinline__ s8v ld8_dual(const void* p, size_t idx, bool isf32) {
    if (isf32) {
        const float* pf = (const float*)p + idx;
        f4v f0 = *(const f4v*)pf;
        f4v f1 = *(const f4v*)(pf + 4);
        s8v r;
        r[0] = (short)bf16bits(f0[0]); r[1] = (short)bf16bits(f0[1]);
        r[2] = (short)bf16bits(f0[2]); r[3] = (short)bf16bits(f0[3]);
        r[4] = (short)bf16bits(f1[0]); r[5] = (short)bf16bits(f1[1]);
        r[6] = (short)bf16bits(f1[2]); r[7] = (short)bf16bits(f1[3]);
        return r;
    }
    return *(const s8v*)((const __hip_bfloat16*)p + idx);
}

__device__ __forceinline__ s8v ld8_ws(const __hip_bfloat16* p) {
    return *(const s8v*)p;
}

// ---------------- dtype detection (fp32 reinterpreted as bf16 -> huge exponents) ----
__global__ void detect_kernel(const ushort* __restrict__ q, int* __restrict__ flag) {
    __shared__ int cnt;
    if (threadIdx.x == 0) cnt = 0;
    __syncthreads();
    int bad = 0;
    #pragma unroll
    for (int i = 0; i < 16; ++i) {
        ushort u = q[threadIdx.x * 16 + i];
        int e = (u >> 7) & 0xFF;
        if (e >= 0x8E) ++bad;
    }
    atomicAdd(&cnt, bad);
    __syncthreads();
    if (threadIdx.x == 0) *flag = (cnt > 100) ? 1 : 0;
}

// ---------------- mask -> bit pack: one wave per 64 cols ----------------
__global__ __launch_bounds__(256) void pack_mask_kernel(
    const int* __restrict__ mask, unsigned long long* __restrict__ mbits)
{
    const size_t widx = (size_t)blockIdx.x * 4 + (threadIdx.x >> 6);
    const int lane = threadIdx.x & 63;
    const int v = mask[widx * 64 + lane];
    const unsigned long long bal = __ballot(v != 0);
    if (lane == 0) mbits[widx] = bal;
}

// ---------------- Q/K projection -> [B,H,L,D] bf16 ----------------
__global__ __launch_bounds__(256) void qk_proj_kernel(
    const void* __restrict__ q_in, const void* __restrict__ k_in,
    const void* __restrict__ Wq,   const void* __restrict__ Wk,
    __hip_bfloat16* __restrict__ qp, __hip_bfloat16* __restrict__ kp,
    const int* __restrict__ flag)
{
    const bool isf32 = (*flag != 0);
    const int which = blockIdx.y;
    const void* X = which == 0 ? q_in : k_in;
    const void* W = which == 0 ? Wq : Wk;
    __hip_bfloat16* dst = which == 0 ? qp : kp;

    const int wave = threadIdx.x >> 6;
    const int lane = threadIdx.x & 63;
    const int quad = lane >> 4;
    const int l16  = lane & 15;
    const int m0 = (blockIdx.x * 4 + wave) * 16;

    const size_t abase = (size_t)(m0 + l16) * D_;
    s8v a0 = ld8_dual(X, abase + quad * 8, isf32);
    s8v a1 = ld8_dual(X, abase + 32 + quad * 8, isf32);

    f4v acc[4];
    #pragma unroll
    for (int nt = 0; nt < 4; ++nt) {
        const size_t bbase = (size_t)(nt * 16 + l16) * D_;
        s8v b0 = ld8_dual(W, bbase + quad * 8, isf32);
        s8v b1 = ld8_dual(W, bbase + 32 + quad * 8, isf32);
        f4v c = {0.f, 0.f, 0.f, 0.f};
        c = mfma16(a0, b0, c);
        c = mfma16(a1, b1, c);
        acc[nt] = c;
    }
    #pragma unroll
    for (int r = 0; r < 4; ++r) {
        const int m = m0 + quad * 4 + r;
        const int h = m & 15;
        const int bl = m >> 4;
        const int b = bl >> 11;
        const int l = bl & (L_ - 1);
        #pragma unroll
        for (int nt = 0; nt < 4; ++nt) {
            const int e = nt * 16 + l16;
            dst[(((size_t)(b * H_ + h)) * L_ + l) * D_ + e] = __float2bfloat16(acc[nt][r]);
        }
    }
}

// ---------------- V projection (transposed output [B,H,D,L]) ----------------
__global__ __launch_bounds__(256) void v_proj_kernel(
    const void* __restrict__ v_in, const void* __restrict__ Wv,
    __hip_bfloat16* __restrict__ vpT, const int* __restrict__ flag)
{
    const bool isf32 = (*flag != 0);
    __shared__ __align__(16) ushort tile[64][72];
    const int wave = threadIdx.x >> 6;
    const int lane = threadIdx.x & 63;
    const int quad = lane >> 4;
    const int l16  = lane & 15;
    const int l0 = blockIdx.x * 64;
    const int bh = blockIdx.y;
    const int b = bh >> 4, h = bh & 15;
    const int lw = l0 + wave * 16;

    const size_t xbase = ((size_t)(b * L_ + lw + l16)) * E_ + h * D_;
    s8v a0 = ld8_dual(v_in, xbase + quad * 8, isf32);
    s8v a1 = ld8_dual(v_in, xbase + 32 + quad * 8, isf32);

    #pragma unroll
    for (int nt = 0; nt < 4; ++nt) {
        const int e = nt * 16 + l16;
        s8v b0 = ld8_dual(Wv, (size_t)e * D_ + quad * 8, isf32);
        s8v b1 = ld8_dual(Wv, (size_t)e * D_ + 32 + quad * 8, isf32);
        f4v c = {0.f, 0.f, 0.f, 0.f};
        c = mfma16(a0, b0, c);
        c = mfma16(a1, b1, c);
        #pragma unroll
        for (int r = 0; r < 4; ++r)
            tile[wave * 16 + quad * 4 + r][e] = bf16bits(c[r]);
    }
    __syncthreads();
    const int e  = threadIdx.x >> 2;
    const int lc = (threadIdx.x & 3) * 16;
    s8v s0, s1;
    #pragma unroll
    for (int i = 0; i < 8; ++i) {
        s0[i] = (short)tile[lc + i][e];
        s1[i] = (short)tile[lc + 8 + i][e];
    }
    __hip_bfloat16* drow = vpT + ((size_t)bh * D_ + e) * L_ + l0 + lc;
    *(s8v*)drow = s0;
    *(s8v*)(drow + 8) = s1;
}

// ---------------- Flash attention, BK=128, barrier-free ----------------
// grid (32 q-tiles, 32 bh); 4 waves x 16 q-rows. exp2 domain: scale = log2e/32.
__global__ __launch_bounds__(256, 4) void attn_kernel(
    const __hip_bfloat16* __restrict__ qp,
    const __hip_bfloat16* __restrict__ kp,
    const __hip_bfloat16* __restrict__ vpT,
    const unsigned long long* __restrict__ mbits,   // [B][L][32] u64
    __hip_bfloat16* __restrict__ attn_out)
{
    __shared__ __align__(16) ushort pbuf[4][16 * 136];   // per-wave 16x128, stride 136
    const int wave = threadIdx.x >> 6;
    const int lane = threadIdx.x & 63;
    const int quad = lane >> 4;
    const int l16  = lane & 15;
    const int bh = blockIdx.y;
    const int b = bh >> 4, h = bh & 15;
    const int q0 = blockIdx.x * 64 + wave * 16;

    const float C2 = 0.045084439755930314f;   // log2(e)/32
    const float NEGBIG = -1.0e20f;

    const __hip_bfloat16* qbase = qp + ((size_t)bh * L_ + q0) * D_;
    s8v qa0 = ld8_ws(qbase + (size_t)l16 * D_ + quad * 8);
    s8v qa1 = ld8_ws(qbase + (size_t)l16 * D_ + 32 + quad * 8);

    float m_i[4], li[4];
    #pragma unroll
    for (int r = 0; r < 4; ++r) { m_i[r] = -1.0e30f; li[r] = 0.f; }
    f4v o[4];
    #pragma unroll
    for (int nt = 0; nt < 4; ++nt) o[nt] = (f4v){0.f, 0.f, 0.f, 0.f};

    const __hip_bfloat16* kbh = kp + (size_t)bh * L_ * D_;
    const __hip_bfloat16* vbh = vpT + (size_t)bh * D_ * L_;
    const uint4* mb4 = (const uint4*)(mbits + (size_t)b * L_ * 32);

    for (int k0 = 0; k0 < L_; k0 += 128) {
        // mask bits: 4 rows x 128 cols, one 16B broadcast load per row
        uint wr[4][4];
        #pragma unroll
        for (int r = 0; r < 4; ++r) {
            const uint4 wq = mb4[(size_t)(q0 + quad * 4 + r) * 16 + (k0 >> 7)];
            wr[r][0] = wq.x; wr[r][1] = wq.y; wr[r][2] = wq.z; wr[r][3] = wq.w;
        }
        // S = Q K^T (16 x 128)
        f4v s[8];
        #pragma unroll
        for (int nt = 0; nt < 8; ++nt) {
            const __hip_bfloat16* krow = kbh + (size_t)(k0 + nt * 16 + l16) * D_;
            s8v kb0 = ld8_ws(krow + quad * 8);
            s8v kb1 = ld8_ws(krow + 32 + quad * 8);
            f4v c = {0.f, 0.f, 0.f, 0.f};
            c = mfma16(qa0, kb0, c);
            c = mfma16(qa1, kb1, c);
            s[nt] = c;
        }
        // mask BEFORE scale (reference order), into exp2 domain
        #pragma unroll
        for (int nt = 0; nt < 8; ++nt) {
            const int sh = ((nt & 1) << 4) + l16;
            #pragma unroll
            for (int r = 0; r < 4; ++r) {
                const uint bit = (wr[r][nt >> 1] >> sh) & 1u;
                const float sv = bit ? s[nt][r] : NEGBIG;
                s[nt][r] = sv * C2;
            }
        }
        // online softmax
        #pragma unroll
        for (int r = 0; r < 4; ++r) {
            float v = s[0][r];
            #pragma unroll
            for (int nt = 1; nt < 8; ++nt) v = fmaxf(v, s[nt][r]);
            #pragma unroll
            for (int off = 1; off < 16; off <<= 1)
                v = fmaxf(v, __shfl_xor(v, off, 64));
            const float mnew = fmaxf(m_i[r], v);
            const float alpha = fast_exp2(m_i[r] - mnew);
            m_i[r] = mnew;
            li[r] *= alpha;
            #pragma unroll
            for (int nt = 0; nt < 4; ++nt) o[nt][r] *= alpha;
        }
        float rsum[4] = {0.f, 0.f, 0.f, 0.f};
        #pragma unroll
        for (int nt = 0; nt < 8; ++nt) {
            #pragma unroll
            for (int r = 0; r < 4; ++r) {
                const float p = fast_exp2(s[nt][r] - m_i[r]);
                rsum[r] += p;
                pbuf[wave][(quad * 4 + r) * 136 + nt * 16 + l16] = bf16bits(p);
            }
        }
        #pragma unroll
        for (int r = 0; r < 4; ++r) {
            float v = rsum[r];
            #pragma unroll
            for (int off = 1; off < 16; off <<= 1)
                v += __shfl_xor(v, off, 64);
            li[r] += v;
        }
        // per-wave LDS RAW fence (no cross-wave sharing -> no s_barrier needed):
        // DS pipe is in-order per wave; this orders compiler + drains lgkm.
        asm volatile("s_waitcnt lgkmcnt(0)" ::: "memory");
        // O += P @ V  (4 k-chunks of 32)
        #pragma unroll
        for (int c = 0; c < 4; ++c) {
            s8v pa = *(const s8v*)&pbuf[wave][l16 * 136 + c * 32 + quad * 8];
            #pragma unroll
            for (int nt = 0; nt < 4; ++nt) {
                const __hip_bfloat16* vrow =
                    vbh + (size_t)(nt * 16 + l16) * L_ + k0 + c * 32 + quad * 8;
                s8v vb = ld8_ws(vrow);
                o[nt] = mfma16(pa, vb, o[nt]);
            }
        }
        // WAR compiler fence: next iter's pbuf stores stay below the pa reads
        asm volatile("" ::: "memory");
    }
    #pragma unroll
    for (int r = 0; r < 4; ++r) {
        const int row = q0 + quad * 4 + r;
        const float inv = 1.0f / li[r];
        #pragma unroll
        for (int nt = 0; nt < 4; ++nt) {
            const int d = nt * 16 + l16;
            attn_out[((size_t)(b * L_ + row)) * E_ + h * D_ + d] =
                __float2bfloat16(o[nt][r] * inv);
        }
    }
}

// ---------------- Wfc/bfc -> bf16 (into dead qp region) ----------------
__global__ __launch_bounds__(256) void cvt_wfc_kernel(
    const void* __restrict__ Wfc, const void* __restrict__ bfc,
    __hip_bfloat16* __restrict__ wfc_bf, __hip_bfloat16* __restrict__ bfc_bf,
    const int* __restrict__ flag)
{
    const bool isf32 = (*flag != 0);
    const size_t base = ((size_t)blockIdx.x * 256 + threadIdx.x) * 4;
    const size_t n1 = (size_t)E_ * E_;
    if (base >= n1 + E_) return;
    const void* src = (base < n1) ? Wfc : bfc;
    const size_t off = (base < n1) ? base : base - n1;
    __hip_bfloat16* dst = (base < n1) ? (wfc_bf + off) : (bfc_bf + off);
    if (isf32) {
        f4v v = *(const f4v*)((const float*)src + off);
        #pragma unroll
        for (int j = 0; j < 4; ++j) dst[j] = __float2bfloat16(v[j]);
    } else {
        *(ushort4*)dst = *(const ushort4*)((const ushort*)src + off);
    }
}

// ---------------- Output FC: out = x @ Wfc^T + bfc ----------------
__global__ __launch_bounds__(256) void fc_kernel(
    const __hip_bfloat16* __restrict__ x,
    const __hip_bfloat16* __restrict__ wfc_bf,
    const __hip_bfloat16* __restrict__ bfc_bf,
    void* __restrict__ out, const int* __restrict__ flag)
{
    const bool isf32 = (*flag != 0);
    const int wave = threadIdx.x >> 6;
    const int lane = threadIdx.x & 63;
    const int quad = lane >> 4;
    const int l16  = lane & 15;
    const int m0 = blockIdx.x * 64 + wave * 16;
    const int n0 = blockIdx.y * 64;

    f4v acc[4];
    #pragma unroll
    for (int nt = 0; nt < 4; ++nt) acc[nt] = (f4v){0.f, 0.f, 0.f, 0.f};

    for (int k0 = 0; k0 < E_; k0 += 32) {
        s8v a = ld8_ws(x + (size_t)(m0 + l16) * E_ + k0 + quad * 8);
        #pragma unroll
        for (int nt = 0; nt < 4; ++nt) {
            s8v bb = ld8_ws(wfc_bf + (size_t)(n0 + nt * 16 + l16) * E_ + k0 + quad * 8);
            acc[nt] = mfma16(a, bb, acc[nt]);
        }
    }
    #pragma unroll
    for (int r = 0; r < 4; ++r) {
        const int m = m0 + quad * 4 + r;
        #pragma unroll
        for (int nt = 0; nt < 4; ++nt) {
            const int n = n0 + nt * 16 + l16;
            const float val = acc[nt][r] + __bfloat162float(bfc_bf[n]);
            if (isf32) ((float*)out)[(size_t)m * E_ + n] = val;
            else       ((__hip_bfloat16*)out)[(size_t)m * E_ + n] = __float2bfloat16(val);
        }
    }
}

extern "C" void kernel_launch(void* const* d_in, const int* in_sizes, int n_in,
                              void* d_out, int out_size, void* d_ws, size_t ws_size,
                              hipStream_t stream) {
    const void* query = d_in[0];
    const void* value = d_in[1];
    const void* key   = d_in[2];
    const int*  mask  = (const int*)d_in[3];
    const void* Wq  = d_in[4];
    const void* Wk  = d_in[5];
    const void* Wv  = d_in[6];
    const void* Wfc = d_in[7];
    const void* bfc = d_in[8];

    char* ws = (char*)d_ws;
    int* flag                     = (int*)ws;
    unsigned long long* mbits     = (unsigned long long*)(ws + (64u << 10));
    __hip_bfloat16* qp            = (__hip_bfloat16*)(ws + (2u  << 20));
    __hip_bfloat16* kp            = (__hip_bfloat16*)(ws + (10u << 20));
    __hip_bfloat16* vpT           = (__hip_bfloat16*)(ws + (18u << 20));
    __hip_bfloat16* attn_out      = (__hip_bfloat16*)(ws + (26u << 20));
    __hip_bfloat16* wfc_bf        = qp;                       // reused after attn
    __hip_bfloat16* bfc_bf        = qp + (size_t)E_ * E_;

    detect_kernel<<<1, 256, 0, stream>>>((const ushort*)query, flag);
    pack_mask_kernel<<<32768, 256, 0, stream>>>(mask, mbits);
    qk_proj_kernel<<<dim3(1024, 2), 256, 0, stream>>>(query, key, Wq, Wk, qp, kp, flag);
    v_proj_kernel<<<dim3(32, 32), 256, 0, stream>>>(value, Wv, vpT, flag);
    attn_kernel<<<dim3(32, 32), 256, 0, stream>>>(qp, kp, vpT, mbits, attn_out);
    cvt_wfc_kernel<<<1025, 256, 0, stream>>>(Wfc, bfc, wfc_bf, bfc_bf, flag);
    fc_kernel<<<dim3(64, 16), 256, 0, stream>>>(attn_out, wfc_bf, bfc_bf, d_out, flag);
}

// Round 6
// 372.117 us; speedup vs baseline: 1.4619x; 1.2779x over previous
//
#include <hip/hip_runtime.h>
#include <hip/hip_bf16.h>

// B=2, L=2048, E=1024, H=16, D=64. Inputs fp32-or-bf16 (detected), mask int32.
// ws: flag@0 | mbits@64KB (1MB) | qp@2MB (8MB, reused for wfc_bf/bfc_bf after attn)
//     | kp@10MB | vpT@18MB | attn_out@26MB   (total 34MB)

#define B_ 2
#define L_ 2048
#define E_ 1024
#define H_ 16
#define D_ 64

typedef __attribute__((ext_vector_type(8))) short s8v;     // 8 bf16
typedef __attribute__((ext_vector_type(4))) float f4v;     // 4 fp32

__device__ __forceinline__ f4v mfma16(s8v a, s8v b, f4v c) {
    return __builtin_amdgcn_mfma_f32_16x16x32_bf16(a, b, c, 0, 0, 0);
}

__device__ __forceinline__ float fast_exp2(float x) {
    return __builtin_amdgcn_exp2f(x);
}

__device__ __forceinline__ ushort bf16bits(float f) {
    __hip_bfloat16 h = __float2bfloat16(f);
    return *(ushort*)&h;
}

// async global->LDS, 16B per lane; LDS dest = base + lane*16 (wave-uniform base)
__device__ __forceinline__ void glds16(const __hip_bfloat16* g, ushort* l) {
    __builtin_amdgcn_global_load_lds(
        (const __attribute__((address_space(1))) void*)g,
        (__attribute__((address_space(3))) void*)l,
        16, 0, 0);
}

__device__ __forceinline__ s8v ld8_dual(const void* p, size_t idx, bool isf32) {
    if (isf32) {
        const float* pf = (const float*)p + idx;
        f4v f0 = *(const f4v*)pf;
        f4v f1 = *(const f4v*)(pf + 4);
        s8v r;
        r[0] = (short)bf16bits(f0[0]); r[1] = (short)bf16bits(f0[1]);
        r[2] = (short)bf16bits(f0[2]); r[3] = (short)bf16bits(f0[3]);
        r[4] = (short)bf16bits(f1[0]); r[5] = (short)bf16bits(f1[1]);
        r[6] = (short)bf16bits(f1[2]); r[7] = (short)bf16bits(f1[3]);
        return r;
    }
    return *(const s8v*)((const __hip_bfloat16*)p + idx);
}

__device__ __forceinline__ s8v ld8_ws(const __hip_bfloat16* p) {
    return *(const s8v*)p;
}

// ---------------- dtype detection ----------------
__global__ void detect_kernel(const ushort* __restrict__ q, int* __restrict__ flag) {
    __shared__ int cnt;
    if (threadIdx.x == 0) cnt = 0;
    __syncthreads();
    int bad = 0;
    #pragma unroll
    for (int i = 0; i < 16; ++i) {
        ushort u = q[threadIdx.x * 16 + i];
        int e = (u >> 7) & 0xFF;
        if (e >= 0x8E) ++bad;
    }
    atomicAdd(&cnt, bad);
    __syncthreads();
    if (threadIdx.x == 0) *flag = (cnt > 100) ? 1 : 0;
}

// ---------------- mask -> bit pack ----------------
__global__ __launch_bounds__(256) void pack_mask_kernel(
    const int* __restrict__ mask, unsigned long long* __restrict__ mbits)
{
    const size_t widx = (size_t)blockIdx.x * 4 + (threadIdx.x >> 6);
    const int lane = threadIdx.x & 63;
    const int v = mask[widx * 64 + lane];
    const unsigned long long bal = __ballot(v != 0);
    if (lane == 0) mbits[widx] = bal;
}

// ---------------- Q/K projection -> [B,H,L,D] bf16 ----------------
__global__ __launch_bounds__(256) void qk_proj_kernel(
    const void* __restrict__ q_in, const void* __restrict__ k_in,
    const void* __restrict__ Wq,   const void* __restrict__ Wk,
    __hip_bfloat16* __restrict__ qp, __hip_bfloat16* __restrict__ kp,
    const int* __restrict__ flag)
{
    const bool isf32 = (*flag != 0);
    const int which = blockIdx.y;
    const void* X = which == 0 ? q_in : k_in;
    const void* W = which == 0 ? Wq : Wk;
    __hip_bfloat16* dst = which == 0 ? qp : kp;

    const int wave = threadIdx.x >> 6;
    const int lane = threadIdx.x & 63;
    const int quad = lane >> 4;
    const int l16  = lane & 15;
    const int m0 = (blockIdx.x * 4 + wave) * 16;

    const size_t abase = (size_t)(m0 + l16) * D_;
    s8v a0 = ld8_dual(X, abase + quad * 8, isf32);
    s8v a1 = ld8_dual(X, abase + 32 + quad * 8, isf32);

    f4v acc[4];
    #pragma unroll
    for (int nt = 0; nt < 4; ++nt) {
        const size_t bbase = (size_t)(nt * 16 + l16) * D_;
        s8v b0 = ld8_dual(W, bbase + quad * 8, isf32);
        s8v b1 = ld8_dual(W, bbase + 32 + quad * 8, isf32);
        f4v c = {0.f, 0.f, 0.f, 0.f};
        c = mfma16(a0, b0, c);
        c = mfma16(a1, b1, c);
        acc[nt] = c;
    }
    #pragma unroll
    for (int r = 0; r < 4; ++r) {
        const int m = m0 + quad * 4 + r;
        const int h = m & 15;
        const int bl = m >> 4;
        const int b = bl >> 11;
        const int l = bl & (L_ - 1);
        #pragma unroll
        for (int nt = 0; nt < 4; ++nt) {
            const int e = nt * 16 + l16;
            dst[(((size_t)(b * H_ + h)) * L_ + l) * D_ + e] = __float2bfloat16(acc[nt][r]);
        }
    }
}

// ---------------- V projection (transposed output [B,H,D,L]) ----------------
__global__ __launch_bounds__(256) void v_proj_kernel(
    const void* __restrict__ v_in, const void* __restrict__ Wv,
    __hip_bfloat16* __restrict__ vpT, const int* __restrict__ flag)
{
    const bool isf32 = (*flag != 0);
    __shared__ __align__(16) ushort tile[64][72];
    const int wave = threadIdx.x >> 6;
    const int lane = threadIdx.x & 63;
    const int quad = lane >> 4;
    const int l16  = lane & 15;
    const int l0 = blockIdx.x * 64;
    const int bh = blockIdx.y;
    const int b = bh >> 4, h = bh & 15;
    const int lw = l0 + wave * 16;

    const size_t xbase = ((size_t)(b * L_ + lw + l16)) * E_ + h * D_;
    s8v a0 = ld8_dual(v_in, xbase + quad * 8, isf32);
    s8v a1 = ld8_dual(v_in, xbase + 32 + quad * 8, isf32);

    #pragma unroll
    for (int nt = 0; nt < 4; ++nt) {
        const int e = nt * 16 + l16;
        s8v b0 = ld8_dual(Wv, (size_t)e * D_ + quad * 8, isf32);
        s8v b1 = ld8_dual(Wv, (size_t)e * D_ + 32 + quad * 8, isf32);
        f4v c = {0.f, 0.f, 0.f, 0.f};
        c = mfma16(a0, b0, c);
        c = mfma16(a1, b1, c);
        #pragma unroll
        for (int r = 0; r < 4; ++r)
            tile[wave * 16 + quad * 4 + r][e] = bf16bits(c[r]);
    }
    __syncthreads();
    const int e  = threadIdx.x >> 2;
    const int lc = (threadIdx.x & 3) * 16;
    s8v s0, s1;
    #pragma unroll
    for (int i = 0; i < 8; ++i) {
        s0[i] = (short)tile[lc + i][e];
        s1[i] = (short)tile[lc + 8 + i][e];
    }
    __hip_bfloat16* drow = vpT + ((size_t)bh * D_ + e) * L_ + l0 + lc;
    *(s8v*)drow = s0;
    *(s8v*)(drow + 8) = s1;
}

// ---------------- Flash attention, BK=64, LDS-staged K (dbuf) + V ----------------
// grid (32 q-tiles, 32 bh), 4 waves x 16 q-rows.
// K/V tiles staged via global_load_lds with XOR chunk swizzle (chunk ^ (row&7)):
// fragment reads then hit 2 lanes/bank (free) instead of 16-way conflicts.
__global__ __launch_bounds__(256, 4) void attn_kernel(
    const __hip_bfloat16* __restrict__ qp,
    const __hip_bfloat16* __restrict__ kp,
    const __hip_bfloat16* __restrict__ vpT,
    const unsigned long long* __restrict__ mbits,   // [B][L][32] u64
    __hip_bfloat16* __restrict__ attn_out)
{
    __shared__ __align__(16) ushort kbuf[2][64 * 64];   // 8KB x2
    __shared__ __align__(16) ushort vbuf[64 * 64];      // 8KB
    __shared__ __align__(16) ushort pbuf[4][16 * 76];   // per-wave P, stride 76

    const int wave = threadIdx.x >> 6;
    const int lane = threadIdx.x & 63;
    const int quad = lane >> 4;
    const int l16  = lane & 15;
    const int sw   = l16 & 7;                 // read-side swizzle key
    const int bh = blockIdx.y;
    const int b = bh >> 4, h = bh & 15;
    const int q0 = blockIdx.x * 64 + wave * 16;

    const float C2 = 0.045084439755930314f;   // log2(e)/32
    const float NEGBIG = -1.0e20f;

    const __hip_bfloat16* kbh = kp + (size_t)bh * L_ * D_;
    const __hip_bfloat16* vbh = vpT + (size_t)bh * D_ * L_;
    const unsigned long long* mrow_bits = mbits + (size_t)b * L_ * 32;

    // staging lane geometry: one glds16 covers 8 rows (64 lanes x 16B = 1KB)
    const int lrow = lane >> 3;                       // 0..7 row within 8-row slab
    const int lchk = (lane & 7) ^ (lrow & 7);         // logical chunk to fetch
    const int r0 = wave * 16;                         // this wave stages rows r0..r0+15
    const __hip_bfloat16* kg0 = kbh + (size_t)(r0 + lrow) * D_ + lchk * 8;
    const __hip_bfloat16* kg1 = kbh + (size_t)(r0 + 8 + lrow) * D_ + lchk * 8;
    const __hip_bfloat16* vg0 = vbh + (size_t)(r0 + lrow) * L_ + lchk * 8;
    const __hip_bfloat16* vg1 = vbh + (size_t)(r0 + 8 + lrow) * L_ + lchk * 8;

    // Q fragments
    const __hip_bfloat16* qbase = qp + ((size_t)bh * L_ + q0) * D_;
    s8v qa0 = ld8_ws(qbase + (size_t)l16 * D_ + quad * 8);
    s8v qa1 = ld8_ws(qbase + (size_t)l16 * D_ + 32 + quad * 8);

    float m_i[4], li[4];
    #pragma unroll
    for (int r = 0; r < 4; ++r) { m_i[r] = -1.0e30f; li[r] = 0.f; }
    f4v o[4];
    #pragma unroll
    for (int nt = 0; nt < 4; ++nt) o[nt] = (f4v){0.f, 0.f, 0.f, 0.f};

    // preload K tile 0
    glds16(kg0, &kbuf[0][r0 * 64]);
    glds16(kg1, &kbuf[0][r0 * 64 + 512]);
    __syncthreads();

    int cur = 0;
    for (int it = 0; it < 32; ++it) {
        const int k0 = it * 64;
        // stage V(it); prefetch K(it+1) into the other buffer
        glds16(vg0 + k0, &vbuf[r0 * 64]);
        glds16(vg1 + k0, &vbuf[r0 * 64 + 512]);
        if (it < 31) {
            glds16(kg0 + (size_t)(k0 + 64) * D_, &kbuf[cur ^ 1][r0 * 64]);
            glds16(kg1 + (size_t)(k0 + 64) * D_, &kbuf[cur ^ 1][r0 * 64 + 512]);
        }
        // mask bits for this 64-col tile
        uint wlo[4], whi[4];
        #pragma unroll
        for (int r = 0; r < 4; ++r) {
            const unsigned long long wq = mrow_bits[(size_t)(q0 + quad * 4 + r) * 32 + it];
            wlo[r] = (uint)wq; whi[r] = (uint)(wq >> 32);
        }
        // S = Q K^T from LDS (swizzled fragments)
        f4v s[4];
        #pragma unroll
        for (int nt = 0; nt < 4; ++nt) {
            const ushort* kr = &kbuf[cur][(nt * 16 + l16) * 64];
            s8v kb0 = *(const s8v*)(kr + ((quad ^ sw) << 3));
            s8v kb1 = *(const s8v*)(kr + (((quad + 4) ^ sw) << 3));
            f4v c = {0.f, 0.f, 0.f, 0.f};
            c = mfma16(qa0, kb0, c);
            c = mfma16(qa1, kb1, c);
            s[nt] = c;
        }
        // mask BEFORE scale (reference order), exp2 domain
        #pragma unroll
        for (int nt = 0; nt < 4; ++nt) {
            const int sh = ((nt & 1) << 4) + l16;
            #pragma unroll
            for (int r = 0; r < 4; ++r) {
                const uint w = (nt & 2) ? whi[r] : wlo[r];
                const float sv = ((w >> sh) & 1u) ? s[nt][r] : NEGBIG;
                s[nt][r] = sv * C2;
            }
        }
        // online softmax
        #pragma unroll
        for (int r = 0; r < 4; ++r) {
            float v = fmaxf(fmaxf(s[0][r], s[1][r]), fmaxf(s[2][r], s[3][r]));
            #pragma unroll
            for (int off = 1; off < 16; off <<= 1)
                v = fmaxf(v, __shfl_xor(v, off, 64));
            const float mnew = fmaxf(m_i[r], v);
            const float alpha = fast_exp2(m_i[r] - mnew);
            m_i[r] = mnew;
            li[r] *= alpha;
            #pragma unroll
            for (int nt = 0; nt < 4; ++nt) o[nt][r] *= alpha;
        }
        float rsum[4] = {0.f, 0.f, 0.f, 0.f};
        #pragma unroll
        for (int nt = 0; nt < 4; ++nt) {
            #pragma unroll
            for (int r = 0; r < 4; ++r) {
                const float p = fast_exp2(s[nt][r] - m_i[r]);
                rsum[r] += p;
                // cheap round-to-nearest bf16 (p >= 0)
                pbuf[wave][(quad * 4 + r) * 76 + nt * 16 + l16] =
                    (ushort)((__float_as_uint(p) + 0x8000u) >> 16);
            }
        }
        #pragma unroll
        for (int r = 0; r < 4; ++r) {
            float v = rsum[r];
            #pragma unroll
            for (int off = 1; off < 16; off <<= 1)
                v += __shfl_xor(v, off, 64);
            li[r] += v;
        }
        // barrier B: V(it) + K(it+1) staged; orders pbuf writes -> reads
        __syncthreads();
        // O += P @ V from LDS
        const ushort* pw = &pbuf[wave][l16 * 76];
        s8v pa0 = *(const s8v*)(pw + quad * 8);
        s8v pa1 = *(const s8v*)(pw + 32 + quad * 8);
        #pragma unroll
        for (int nt = 0; nt < 4; ++nt) {
            const ushort* vr = &vbuf[(nt * 16 + l16) * 64];
            s8v vb0 = *(const s8v*)(vr + ((quad ^ sw) << 3));
            s8v vb1 = *(const s8v*)(vr + (((quad + 4) ^ sw) << 3));
            o[nt] = mfma16(pa0, vb0, o[nt]);
            o[nt] = mfma16(pa1, vb1, o[nt]);
        }
        cur ^= 1;
        // barrier A: PV done before next iter overwrites vbuf / pbuf
        __syncthreads();
    }
    #pragma unroll
    for (int r = 0; r < 4; ++r) {
        const int row = q0 + quad * 4 + r;
        const float inv = 1.0f / li[r];
        #pragma unroll
        for (int nt = 0; nt < 4; ++nt) {
            const int d = nt * 16 + l16;
            attn_out[((size_t)(b * L_ + row)) * E_ + h * D_ + d] =
                __float2bfloat16(o[nt][r] * inv);
        }
    }
}

// ---------------- Wfc/bfc -> bf16 (into dead qp region) ----------------
__global__ __launch_bounds__(256) void cvt_wfc_kernel(
    const void* __restrict__ Wfc, const void* __restrict__ bfc,
    __hip_bfloat16* __restrict__ wfc_bf, __hip_bfloat16* __restrict__ bfc_bf,
    const int* __restrict__ flag)
{
    const bool isf32 = (*flag != 0);
    const size_t base = ((size_t)blockIdx.x * 256 + threadIdx.x) * 4;
    const size_t n1 = (size_t)E_ * E_;
    if (base >= n1 + E_) return;
    const void* src = (base < n1) ? Wfc : bfc;
    const size_t off = (base < n1) ? base : base - n1;
    __hip_bfloat16* dst = (base < n1) ? (wfc_bf + off) : (bfc_bf + off);
    if (isf32) {
        f4v v = *(const f4v*)((const float*)src + off);
        #pragma unroll
        for (int j = 0; j < 4; ++j) dst[j] = __float2bfloat16(v[j]);
    } else {
        *(ushort4*)dst = *(const ushort4*)((const ushort*)src + off);
    }
}

// ---------------- Output FC: out = x @ Wfc^T + bfc ----------------
__global__ __launch_bounds__(256) void fc_kernel(
    const __hip_bfloat16* __restrict__ x,
    const __hip_bfloat16* __restrict__ wfc_bf,
    const __hip_bfloat16* __restrict__ bfc_bf,
    void* __restrict__ out, const int* __restrict__ flag)
{
    const bool isf32 = (*flag != 0);
    const int wave = threadIdx.x >> 6;
    const int lane = threadIdx.x & 63;
    const int quad = lane >> 4;
    const int l16  = lane & 15;
    const int m0 = blockIdx.x * 64 + wave * 16;
    const int n0 = blockIdx.y * 64;

    f4v acc[4];
    #pragma unroll
    for (int nt = 0; nt < 4; ++nt) acc[nt] = (f4v){0.f, 0.f, 0.f, 0.f};

    for (int k0 = 0; k0 < E_; k0 += 32) {
        s8v a = ld8_ws(x + (size_t)(m0 + l16) * E_ + k0 + quad * 8);
        #pragma unroll
        for (int nt = 0; nt < 4; ++nt) {
            s8v bb = ld8_ws(wfc_bf + (size_t)(n0 + nt * 16 + l16) * E_ + k0 + quad * 8);
            acc[nt] = mfma16(a, bb, acc[nt]);
        }
    }
    #pragma unroll
    for (int r = 0; r < 4; ++r) {
        const int m = m0 + quad * 4 + r;
        #pragma unroll
        for (int nt = 0; nt < 4; ++nt) {
            const int n = n0 + nt * 16 + l16;
            const float val = acc[nt][r] + __bfloat162float(bfc_bf[n]);
            if (isf32) ((float*)out)[(size_t)m * E_ + n] = val;
            else       ((__hip_bfloat16*)out)[(size_t)m * E_ + n] = __float2bfloat16(val);
        }
    }
}

extern "C" void kernel_launch(void* const* d_in, const int* in_sizes, int n_in,
                              void* d_out, int out_size, void* d_ws, size_t ws_size,
                              hipStream_t stream) {
    const void* query = d_in[0];
    const void* value = d_in[1];
    const void* key   = d_in[2];
    const int*  mask  = (const int*)d_in[3];
    const void* Wq  = d_in[4];
    const void* Wk  = d_in[5];
    const void* Wv  = d_in[6];
    const void* Wfc = d_in[7];
    const void* bfc = d_in[8];

    char* ws = (char*)d_ws;
    int* flag                     = (int*)ws;
    unsigned long long* mbits     = (unsigned long long*)(ws + (64u << 10));
    __hip_bfloat16* qp            = (__hip_bfloat16*)(ws + (2u  << 20));
    __hip_bfloat16* kp            = (__hip_bfloat16*)(ws + (10u << 20));
    __hip_bfloat16* vpT           = (__hip_bfloat16*)(ws + (18u << 20));
    __hip_bfloat16* attn_out      = (__hip_bfloat16*)(ws + (26u << 20));
    __hip_bfloat16* wfc_bf        = qp;                       // reused after attn
    __hip_bfloat16* bfc_bf        = qp + (size_t)E_ * E_;

    detect_kernel<<<1, 256, 0, stream>>>((const ushort*)query, flag);
    pack_mask_kernel<<<32768, 256, 0, stream>>>(mask, mbits);
    qk_proj_kernel<<<dim3(1024, 2), 256, 0, stream>>>(query, key, Wq, Wk, qp, kp, flag);
    v_proj_kernel<<<dim3(32, 32), 256, 0, stream>>>(value, Wv, vpT, flag);
    attn_kernel<<<dim3(32, 32), 256, 0, stream>>>(qp, kp, vpT, mbits, attn_out);
    cvt_wfc_kernel<<<1025, 256, 0, stream>>>(Wfc, bfc, wfc_bf, bfc_bf, flag);
    fc_kernel<<<dim3(64, 16), 256, 0, stream>>>(attn_out, wfc_bf, bfc_bf, d_out, flag);
}